// Round 9
// baseline (125.367 us; speedup 1.0000x reference)
//
#include <hip/hip_runtime.h>
#include <math.h>

#define S_LEN 2048
#define NB    2
#define CQ_   256
#define CC_   256
#define DH    50
#define KW    101
#define PS    100
#define WTH   1e-5f // phase-C weight skip threshold

#define NB2   384   // padded B-matrix width: 256 V cols + 100 hidden + 28 zero
#define MT    64    // GEMM M tile
#define NT    64    // GEMM N tile
#define KC    32    // GEMM K chunk

// ---------------------------------------------------------------------------
// k_prep: BT[c][n] = n<256 ? Wa[c][n] : (n<356 ? Wp[n-256][c] : 0).
// NOTE (R8 bug): the V half needs Wa UNTRANSPOSED — V[q] = sum_c ct[c]*Wa[c][q]
// so BT[c][n] = Wa[c*CQ+n]  (R8 wrote Wa[n*CQ+c] -> absmax 5.9).
// Block c, thread n: both read and write contiguous in n -> coalesced.
// ---------------------------------------------------------------------------
__global__ __launch_bounds__(NB2) void k_prep(const float* __restrict__ Wa,
    const float* __restrict__ Wp, float* __restrict__ BT) {
  const int c = blockIdx.x, n = threadIdx.x;
  float v = 0.0f;
  if (n < CQ_)            v = Wa[(size_t)c * CQ_ + n];          // Wa[c][n]
  else if (n < CQ_ + PS)  v = Wp[(size_t)(n - CQ_) * CC_ + c];  // Wp[j][c]
  BT[(size_t)c * NB2 + n] = v;
}

// ---------------------------------------------------------------------------
// k_gemm: G[4096][384] = ct[4096][256] @ BT[256][384].
// Classic register-blocked tiled GEMM: 64x64 tile, 256 thr, 4x4 acc/thread,
// K-chunks of 32 staged in LDS (coalesced float4 global loads; A transposed
// on store). 16 FMA per 2 ds_read_b128 — the load amortization k_align's
// 1-col-per-thread structure never had (R5/R6/R7 all plateaued ~36us).
// Cols 0..255 = V, 256..355 = hidden pre-activations (tanh'd later in k_p).
// ---------------------------------------------------------------------------
__global__ __launch_bounds__(256) void k_gemm(const float* __restrict__ ct,
    const float* __restrict__ BT, float* __restrict__ G) {
  const int bm = blockIdx.x & 63;          // 64 M tiles
  const int bn = blockIdx.x >> 6;          // 6 N tiles
  const int r0 = bm * MT;
  const int n0 = bn * NT;
  const int tid = threadIdx.x;
  const int tx = tid & 15, ty = tid >> 4;  // 16x16 thread grid, 4x4 each

  __shared__ float As[KC][MT + 4];         // stride 68 floats
  __shared__ float Bs[KC][NT + 4];

  float acc[4][4];
#pragma unroll
  for (int i = 0; i < 4; ++i)
#pragma unroll
    for (int j = 0; j < 4; ++j) acc[i][j] = 0.0f;

  const int kq = tid & 7,  mA = tid >> 3;  // A-stage: k-quad, m-row (0..31)
  const int nq = tid & 15, kB = tid >> 4;  // B-stage: n-quad, k-row (0..15)

  for (int c0 = 0; c0 < CC_; c0 += KC) {
    // global loads first (coalesced float4 along the contiguous dim)
    const float4 a0 = *(const float4*)&ct[(size_t)(r0 + mA) * CC_ + c0 + kq * 4];
    const float4 a1 = *(const float4*)&ct[(size_t)(r0 + mA + 32) * CC_ + c0 + kq * 4];
    const float4 b0 = *(const float4*)&BT[(size_t)(c0 + kB) * NB2 + n0 + nq * 4];
    const float4 b1 = *(const float4*)&BT[(size_t)(c0 + kB + 16) * NB2 + n0 + nq * 4];
    __syncthreads();                       // previous chunk's reads done
    As[kq * 4 + 0][mA] = a0.x;
    As[kq * 4 + 1][mA] = a0.y;
    As[kq * 4 + 2][mA] = a0.z;
    As[kq * 4 + 3][mA] = a0.w;
    As[kq * 4 + 0][mA + 32] = a1.x;
    As[kq * 4 + 1][mA + 32] = a1.y;
    As[kq * 4 + 2][mA + 32] = a1.z;
    As[kq * 4 + 3][mA + 32] = a1.w;
    *(float4*)&Bs[kB][nq * 4]      = b0;
    *(float4*)&Bs[kB + 16][nq * 4] = b1;
    __syncthreads();
#pragma unroll
    for (int k = 0; k < KC; ++k) {         // k ascending: deterministic order
      const float4 av = *(const float4*)&As[k][ty * 4];
      const float4 bv = *(const float4*)&Bs[k][tx * 4];
      const float a[4] = {av.x, av.y, av.z, av.w};
      const float b[4] = {bv.x, bv.y, bv.z, bv.w};
#pragma unroll
      for (int i = 0; i < 4; ++i)
#pragma unroll
        for (int j = 0; j < 4; ++j) acc[i][j] = fmaf(a[i], b[j], acc[i][j]);
    }
  }

#pragma unroll
  for (int i = 0; i < 4; ++i) {
    float4 o;
    o.x = acc[i][0]; o.y = acc[i][1]; o.z = acc[i][2]; o.w = acc[i][3];
    *(float4*)&G[(size_t)(r0 + ty * 4 + i) * NB2 + n0 + tx * 4] = o;
  }
}

// ---------------------------------------------------------------------------
// k_p: one thread per row. Preload H[0..99] into registers (25 independent
// float4 — no serial load chain), then STRICT left-to-right j-sum
// s += Vp[j]*tanhf(H[j])  (same order as all passing rounds; trunc(p)
// boundaries are discontinuous), sigmoid via expf as before.
// ---------------------------------------------------------------------------
__global__ __launch_bounds__(256) void k_p(const float* __restrict__ G,
    const float* __restrict__ Vp, float* __restrict__ p_out) {
  const int r = blockIdx.x * 256 + threadIdx.x;
  const float* h = G + (size_t)r * NB2 + CQ_;
  float H[PS];
#pragma unroll
  for (int j = 0; j < PS; j += 4) {
    const float4 v = *(const float4*)&h[j];
    H[j + 0] = v.x; H[j + 1] = v.y; H[j + 2] = v.z; H[j + 3] = v.w;
  }
  float s = 0.0f;
#pragma unroll
  for (int j = 0; j < PS; ++j) s += Vp[j] * tanhf(H[j]);   // strict order
  p_out[r] = (float)S_LEN * (1.0f / (1.0f + expf(-s)));
}

// ---------------------------------------------------------------------------
// k_attn: one row per wave (V from ws G, stride 384; out not aliased).
//  Phase A: 13 paired steps, 8 float4 loads in flight; stripe dot + 4
//   subgroup shfl_xor per score.  Phase B: wave softmax + gaussian weights.
//  Phase C: batch-4 ballot survivor walk (w > 1e-5).
// ---------------------------------------------------------------------------
__global__ __launch_bounds__(256, 4) void k_attn(const float* __restrict__ q,
    const float* __restrict__ p_in, const float* __restrict__ G,
    float* __restrict__ out) {
  const int wid  = threadIdx.x >> 6;
  const int row  = (blockIdx.x << 2) + wid;
  const int lane = threadIdx.x & 63;
  const int b    = row >> 11;

  __shared__ float ss[4][128];   // scores (101..127 = -inf)
  __shared__ float sw[4][128];   // final weights

  const float p  = p_in[row];
  const float tp = truncf(p);
  const float* qb = q + (size_t)b * S_LEN * CQ_;

  const int sub = lane >> 4;          // window-slot within group
  const int cb  = (lane & 15) * 16;   // column stripe base

  const float* vrow = G + (size_t)row * NB2 + cb;
  const float4 v0 = *(const float4*)(vrow);
  const float4 v1 = *(const float4*)(vrow + 4);
  const float4 v2 = *(const float4*)(vrow + 8);
  const float4 v3 = *(const float4*)(vrow + 12);

  if (lane >= KW - 64) ss[wid][64 + lane] = -INFINITY;   // slots 101..127

  for (int g = 0; g < 26; g += 2) {
    const int ka = (g << 2) + sub;                 // uniform per 16-subgroup
    const int kb = ka + 4;
    const float ta = p + (float)(ka - DH) + 1.0f;  // ref op order
    const float tb = p + (float)(kb - DH) + 1.0f;
    const int rawa = (int)ta;                      // trunc toward zero
    const int rawb = (int)tb;
    const bool oka = (rawa >= 1) && (rawa <= S_LEN) && (ka < KW);
    const bool okb = (rawb >= 1) && (rawb <= S_LEN) && (kb < KW);
    const float* qra = qb + (size_t)(oka ? rawa - 1 : 0) * CQ_ + cb;
    const float* qrb = qb + (size_t)(okb ? rawb - 1 : 0) * CQ_ + cb;

    const float4 a0 = *(const float4*)(qra);
    const float4 a1 = *(const float4*)(qra + 4);
    const float4 a2 = *(const float4*)(qra + 8);
    const float4 a3 = *(const float4*)(qra + 12);
    const float4 b0 = *(const float4*)(qrb);
    const float4 b1 = *(const float4*)(qrb + 4);
    const float4 b2 = *(const float4*)(qrb + 8);
    const float4 b3 = *(const float4*)(qrb + 12);

    float t0 = a0.x * v0.x, t1 = a1.x * v1.x, t2 = a2.x * v2.x, t3 = a3.x * v3.x;
    t0 = fmaf(a0.y, v0.y, t0); t1 = fmaf(a1.y, v1.y, t1);
    t2 = fmaf(a2.y, v2.y, t2); t3 = fmaf(a3.y, v3.y, t3);
    t0 = fmaf(a0.z, v0.z, t0); t1 = fmaf(a1.z, v1.z, t1);
    t2 = fmaf(a2.z, v2.z, t2); t3 = fmaf(a3.z, v3.z, t3);
    t0 = fmaf(a0.w, v0.w, t0); t1 = fmaf(a1.w, v1.w, t1);
    t2 = fmaf(a2.w, v2.w, t2); t3 = fmaf(a3.w, v3.w, t3);
    float sA = (t0 + t1) + (t2 + t3);
    sA += __shfl_xor(sA, 1, 64);
    sA += __shfl_xor(sA, 2, 64);
    sA += __shfl_xor(sA, 4, 64);
    sA += __shfl_xor(sA, 8, 64);
    sA = oka ? sA : -INFINITY;
    if ((lane & 15) == 0) ss[wid][ka] = sA;

    float u0 = b0.x * v0.x, u1 = b1.x * v1.x, u2 = b2.x * v2.x, u3 = b3.x * v3.x;
    u0 = fmaf(b0.y, v0.y, u0); u1 = fmaf(b1.y, v1.y, u1);
    u2 = fmaf(b2.y, v2.y, u2); u3 = fmaf(b3.y, v3.y, u3);
    u0 = fmaf(b0.z, v0.z, u0); u1 = fmaf(b1.z, v1.z, u1);
    u2 = fmaf(b2.z, v2.z, u2); u3 = fmaf(b3.z, v3.z, u3);
    u0 = fmaf(b0.w, v0.w, u0); u1 = fmaf(b1.w, v1.w, u1);
    u2 = fmaf(b2.w, v2.w, u2); u3 = fmaf(b3.w, v3.w, u3);
    float sB = (u0 + u1) + (u2 + u3);
    sB += __shfl_xor(sB, 1, 64);
    sB += __shfl_xor(sB, 2, 64);
    sB += __shfl_xor(sB, 4, 64);
    sB += __shfl_xor(sB, 8, 64);
    sB = okb ? sB : -INFINITY;
    if ((lane & 15) == 0) ss[wid][kb] = sB;
  }

  const float s0 = ss[wid][lane];
  const float s1 = ss[wid][64 + lane];

  float m = fmaxf(s0, s1);
#pragma unroll
  for (int off = 1; off < 64; off <<= 1) m = fmaxf(m, __shfl_xor(m, off, 64));

  const float e0 = __expf(s0 - m);                  // -inf -> 0
  const float e1 = __expf(s1 - m);
  float den = e0 + e1;
#pragma unroll
  for (int off = 1; off < 64; off <<= 1) den += __shfl_xor(den, off, 64);
  const float inv = 1.0f / den;

  float g0 = ((float)(lane - DH) + tp - p) / (float)DH;        // k = lane
  float g1 = ((float)(lane + (64 - DH)) + tp - p) / (float)DH; // k = 64+lane
  const float w0 = e0 * __expf(-2.0f * g0 * g0) * inv;
  const float w1 = e1 * __expf(-2.0f * g1 * g1) * inv;
  sw[wid][lane] = w0;
  if (lane < KW - 64) sw[wid][64 + lane] = w1;
  // wave-private LDS rows: intra-wave lgkmcnt ordering suffices

  unsigned long long m0 = __ballot(w0 > WTH);
  unsigned long long m1 = __ballot((lane < KW - 64) && (w1 > WTH));

  float4 acc = make_float4(0.0f, 0.0f, 0.0f, 0.0f);
  while ((m0 | m1) != 0ull) {
    int kk[4];
#pragma unroll
    for (int i = 0; i < 4; ++i) {
      int k = -1;
      if (m0)      { k = __builtin_ctzll(m0);      m0 &= m0 - 1; }
      else if (m1) { k = 64 + __builtin_ctzll(m1); m1 &= m1 - 1; }
      kk[i] = k;
    }
#pragma unroll
    for (int i = 0; i < 4; ++i) {
      if (kk[i] >= 0) {                             // wave-uniform
        const float wk = sw[wid][kk[i]];
        const float t = p + (float)(kk[i] - DH) + 1.0f;
        const int r = (int)t - 1;                   // w>0 implies valid
        const float4 qv = *(const float4*)(qb + (size_t)r * CQ_ + lane * 4);
        acc.x = fmaf(wk, qv.x, acc.x);
        acc.y = fmaf(wk, qv.y, acc.y);
        acc.z = fmaf(wk, qv.z, acc.z);
        acc.w = fmaf(wk, qv.w, acc.w);
      }
    }
  }
  *(float4*)(out + (size_t)row * CQ_ + lane * 4) = acc;
}

// ---------------------------------------------------------------------------
extern "C" void kernel_launch(void* const* d_in, const int* in_sizes, int n_in,
                              void* d_out, int out_size, void* d_ws, size_t ws_size,
                              hipStream_t stream) {
  const float* q  = (const float*)d_in[0];
  const float* ct = (const float*)d_in[1];
  const float* Wa = (const float*)d_in[2];
  const float* Wp = (const float*)d_in[3];
  const float* Vp = (const float*)d_in[4];
  float* out = (float*)d_out;

  // ws (floats): p[4096] | BT[256*384] | G[4096*384]   (~6.7 MB of 268 MB ws)
  float* ws    = (float*)d_ws;
  float* p_ws  = ws;
  float* BT_ws = ws + NB * S_LEN;
  float* G_ws  = BT_ws + (size_t)CC_ * NB2;

  k_prep<<<CC_, NB2, 0, stream>>>(Wa, Wp, BT_ws);
  k_gemm<<<64 * 6, 256, 0, stream>>>(ct, BT_ws, G_ws);
  k_p   <<<(NB * S_LEN) / 256, 256, 0, stream>>>(G_ws, Vp, p_ws);
  k_attn<<<(NB * S_LEN) / 4, 256, 0, stream>>>(q, p_ws, G_ws, out);
}